// Round 10
// baseline (11288.118 us; speedup 1.0000x reference)
//
#include <hip/hip_runtime.h>
#include <hip/hip_bf16.h>
#include <stdint.h>

// Problem constants
#define NB 128    // batch
#define NT 512    // time steps
#define ND 256    // input dim
#define NH 1024   // hidden dim
#define NZ 128    // latent dim
#define NG 4096   // 4*NH gate width

typedef __attribute__((ext_vector_type(8))) __bf16 bf16x8;
typedef __attribute__((ext_vector_type(4))) __bf16 bf16x4;
typedef __attribute__((ext_vector_type(4))) float floatx4;

// Fast native transcendentals (v_exp_f32 / v_log_f32 / v_rcp_f32).
__device__ __forceinline__ float fsigmoid_(float x) {
  return __fdividef(1.0f, 1.0f + __expf(-x));
}
__device__ __forceinline__ float fsoftplus_(float x) {
  return fmaxf(x, 0.0f) + __logf(1.0f + __expf(-fabsf(x)));
}

// B-fragment loader: 8 fp32 rows (stride NG) -> bf16x8
__device__ __forceinline__ bf16x8 load_bfrag(const float* s) {
  bf16x8 v;
#pragma unroll
  for (int jj = 0; jj < 8; ++jj) v[jj] = (__bf16)s[jj * NG];
  return v;
}

// ---------------------------------------------------------------------------
// Kernel 1: convert x (B,T,D) fp32 -> xb (T,B,D) bf16
// ---------------------------------------------------------------------------
__global__ __launch_bounds__(256) void convert_x_kernel(
    const float4* __restrict__ x, __bf16* __restrict__ xb) {
  int i = blockIdx.x * 256 + threadIdx.x;
  int d4 = i & 63;
  int bt = i >> 6;
  int b = bt >> 9;
  int t = bt & 511;
  float4 v = x[i];
  bf16x4 o;
  o[0] = (__bf16)v.x; o[1] = (__bf16)v.y; o[2] = (__bf16)v.z; o[3] = (__bf16)v.w;
  *(bf16x4*)(xb + ((t * NB + b) * ND + d4 * 4)) = o;
}

// ---------------------------------------------------------------------------
// Kernel 2: persistent LSTM.
// Grid 256 WGs x 512 thr (1 WG/CU, cooperative). WG = (m_blk = blockIdx&7,
// n_blk = blockIdx>>3): batch rows [m_blk*16,+16), h-cols [n_blk*32,+32).
// Wave w owns a unique K-eighth for all 4 gates (R9): x-rows [w*32,+32),
// h-rows [w*128,+128); 40 B-frags = 160 VGPRs; partials reduce via Gs[8].
//
// R10: h exchanged through hfrag, laid out in CONSUMER A-FRAGMENT ORDER:
//   hfrag[buf][m_blk][src_n][(q*16+row16)*8 + c8]   (bf16)
// so consumer wave w's fragment j is one contiguous 1KB block read as
// base + lane*16 (perfectly coalesced; R9's row-strided loads were 512
// scattered 8B requests/wave — why R9 was neutral). Producer thread
// (r_e,c_e) writes (q=c_e>>3, row16=r_e, c8=c_e&7) — 8B packed via shfl.
// R10: per-producer-WAVE sub-slots (8/WG): wave v releases rows 2v,2v+1
// after its OWN vmcnt drain (no full-WG S3 barrier). Consumer lane (q,n16)
// polls sub-slot (src=w*4+q, v=n16>>1); __all covers all 32 events.
// R10: As x-LDS tile gone — per-wave x A-frag loaded global->VGPR after
// release, consumed by XPHASE during the poll wait.
// Syncs/step: ONE __syncthreads (gate reduction).
// ---------------------------------------------------------------------------
__global__ __launch_bounds__(512, 1) void lstm_persistent(
    const __bf16* __restrict__ xb,    // (T, B, D) bf16
    const float* __restrict__ W,      // (D, 4H)
    const float* __restrict__ U,      // (H, 4H)
    const float* __restrict__ bias,   // (4H)
    __bf16* __restrict__ hfrag,       // 2 x 8 x 32 x 512 bf16 (fragment layout)
    float* __restrict__ hlast,        // B * H fp32
    unsigned int* __restrict__ slots) // 2048 sub-slots: (m*32+n)*8 + wave
{
  const int tid = threadIdx.x;
  const int wg = blockIdx.x;
  const int m_blk = wg & 7;
  const int n_blk = wg >> 3;
  const int wave = tid >> 6;
  const int lane = tid & 63;
  const int q = lane >> 4;     // k-quad
  const int n16 = lane & 15;   // MFMA row (A) / col (B) within 16

  __shared__ float Gs[8][16][132];   // per-wave gate partials, 128+4 pad

  // ---- Gate-column bases (4 gates x 2 col-halves) ----
  const int nb = n_blk * 32 + n16;
  const int c00 = nb,            c01 = nb + 16;
  const int c10 = NH + nb,       c11 = NH + nb + 16;
  const int c20 = 2 * NH + nb,   c21 = 2 * NH + nb + 16;
  const int c30 = 3 * NH + nb,   c31 = 3 * NH + nb + 16;

  // ---- Persistent B fragments ----
  const float* Wb = W + (wave * 32 + q * 8) * NG;
  bf16x8 BX00 = load_bfrag(Wb + c00), BX01 = load_bfrag(Wb + c01);
  bf16x8 BX10 = load_bfrag(Wb + c10), BX11 = load_bfrag(Wb + c11);
  bf16x8 BX20 = load_bfrag(Wb + c20), BX21 = load_bfrag(Wb + c21);
  bf16x8 BX30 = load_bfrag(Wb + c30), BX31 = load_bfrag(Wb + c31);
  const float* Ub = U + (wave * 128 + q * 8) * NG;
#define DECL_J(J)                                                       \
  bf16x8 BH00##J = load_bfrag(Ub + (J) * 32 * NG + c00);                \
  bf16x8 BH01##J = load_bfrag(Ub + (J) * 32 * NG + c01);                \
  bf16x8 BH10##J = load_bfrag(Ub + (J) * 32 * NG + c10);                \
  bf16x8 BH11##J = load_bfrag(Ub + (J) * 32 * NG + c11);                \
  bf16x8 BH20##J = load_bfrag(Ub + (J) * 32 * NG + c20);                \
  bf16x8 BH21##J = load_bfrag(Ub + (J) * 32 * NG + c21);                \
  bf16x8 BH30##J = load_bfrag(Ub + (J) * 32 * NG + c30);                \
  bf16x8 BH31##J = load_bfrag(Ub + (J) * 32 * NG + c31);
  DECL_J(0) DECL_J(1) DECL_J(2) DECL_J(3)
#undef DECL_J

  // Bias folded into wave 0's accumulator init only (partials are summed)
  const float b00 = (wave == 0) ? bias[c00] : 0.f;
  const float b01 = (wave == 0) ? bias[c01] : 0.f;
  const float b10 = (wave == 0) ? bias[c10] : 0.f;
  const float b11 = (wave == 0) ? bias[c11] : 0.f;
  const float b20 = (wave == 0) ? bias[c20] : 0.f;
  const float b21 = (wave == 0) ? bias[c21] : 0.f;
  const float b30 = (wave == 0) ? bias[c30] : 0.f;
  const float b31 = (wave == 0) ? bias[c31] : 0.f;

  // ---- Elementwise-role constants ----
  const int r_e = tid >> 5;            // 0..15 row
  const int c_e = tid & 31;            // 0..31 h-col
  const int hcol = n_blk * 32 + c_e;
  const int grow = m_blk * 16 + r_e;
  float c_state = 0.0f;

  // Sub-slot indices
  const int my_slot = (m_blk * 32 + n_blk) * 8 + wave;             // release
  const unsigned int* poll_p =
      &slots[(m_blk * 32 + wave * 4 + q) * 8 + (n16 >> 1)];        // poll
  // Producer publish offset (fragment layout), consumer fragment base
  const int pub_off = m_blk * 16384 + n_blk * 512
                    + ((c_e >> 3) * 16 + r_e) * 8 + (c_e & 7);
  const int con_off = m_blk * 16384 + (wave * 4) * 512 + lane * 8;

#define MFMA_(a, b, acc) __builtin_amdgcn_mfma_f32_16x16x32_bf16(a, b, acc, 0, 0, 0)
#define AL(p) __hip_atomic_load(p, __ATOMIC_RELAXED, __HIP_MEMORY_SCOPE_AGENT)

  floatx4 AC00, AC01, AC10, AC11, AC20, AC21, AC30, AC31;
  bf16x8 XF;  // x A-fragment: rows n16, cols wave*32+q*8 (per-wave, in regs)
#define XPHASE()                                                        \
  {                                                                     \
    AC00 = (floatx4){b00, b00, b00, b00}; AC01 = (floatx4){b01, b01, b01, b01}; \
    AC10 = (floatx4){b10, b10, b10, b10}; AC11 = (floatx4){b11, b11, b11, b11}; \
    AC20 = (floatx4){b20, b20, b20, b20}; AC21 = (floatx4){b21, b21, b21, b21}; \
    AC30 = (floatx4){b30, b30, b30, b30}; AC31 = (floatx4){b31, b31, b31, b31}; \
    AC00 = MFMA_(XF, BX00, AC00); AC01 = MFMA_(XF, BX01, AC01);         \
    AC10 = MFMA_(XF, BX10, AC10); AC11 = MFMA_(XF, BX11, AC11);         \
    AC20 = MFMA_(XF, BX20, AC20); AC21 = MFMA_(XF, BX21, AC21);         \
    AC30 = MFMA_(XF, BX30, AC30); AC31 = MFMA_(XF, BX31, AC31);         \
  }

  // ---- Prologue: x(0) fragment + x-phase ----
  XF = *(const bf16x8*)(xb + (m_blk * 16 + n16) * ND + wave * 32 + q * 8);
  XPHASE()

  for (int t = 0; t < NT; ++t) {
    // ---- Wait for my 32 source events (t=0 passes: slots start at 0) ----
    {
      const unsigned tgt = (unsigned)t;
      while (true) {
        unsigned v = AL(poll_p);
        if (__all((int)(v >= tgt))) break;
        __builtin_amdgcn_s_sleep(1);
      }
      __asm__ __volatile__("" ::: "memory");  // no hoisting of h loads
    }

    // ---- Coalesced fragment loads: 4 x (base + lane*16), then 32 MFMAs ----
    {
      const __bf16* fb = hfrag + (t & 1) * 131072 + con_off;
      union { unsigned long long u[2]; bf16x8 v; } u0, u1, u2, u3;
      const unsigned long long* p0 = (const unsigned long long*)fb;
      const unsigned long long* p1 = (const unsigned long long*)(fb + 512);
      const unsigned long long* p2 = (const unsigned long long*)(fb + 1024);
      const unsigned long long* p3 = (const unsigned long long*)(fb + 1536);
      u0.u[0] = AL(p0); u0.u[1] = AL(p0 + 1);
      u1.u[0] = AL(p1); u1.u[1] = AL(p1 + 1);
      u2.u[0] = AL(p2); u2.u[1] = AL(p2 + 1);
      u3.u[0] = AL(p3); u3.u[1] = AL(p3 + 1);
      bf16x8 a0 = u0.v, a1 = u1.v, a2 = u2.v, a3 = u3.v;
      AC00 = MFMA_(a0, BH000, AC00); AC01 = MFMA_(a0, BH010, AC01);
      AC10 = MFMA_(a0, BH100, AC10); AC11 = MFMA_(a0, BH110, AC11);
      AC20 = MFMA_(a0, BH200, AC20); AC21 = MFMA_(a0, BH210, AC21);
      AC30 = MFMA_(a0, BH300, AC30); AC31 = MFMA_(a0, BH310, AC31);
      AC00 = MFMA_(a1, BH001, AC00); AC01 = MFMA_(a1, BH011, AC01);
      AC10 = MFMA_(a1, BH101, AC10); AC11 = MFMA_(a1, BH111, AC11);
      AC20 = MFMA_(a1, BH201, AC20); AC21 = MFMA_(a1, BH211, AC21);
      AC30 = MFMA_(a1, BH301, AC30); AC31 = MFMA_(a1, BH311, AC31);
      AC00 = MFMA_(a2, BH002, AC00); AC01 = MFMA_(a2, BH012, AC01);
      AC10 = MFMA_(a2, BH102, AC10); AC11 = MFMA_(a2, BH112, AC11);
      AC20 = MFMA_(a2, BH202, AC20); AC21 = MFMA_(a2, BH212, AC21);
      AC30 = MFMA_(a2, BH302, AC30); AC31 = MFMA_(a2, BH312, AC31);
      AC00 = MFMA_(a3, BH003, AC00); AC01 = MFMA_(a3, BH013, AC01);
      AC10 = MFMA_(a3, BH103, AC10); AC11 = MFMA_(a3, BH113, AC11);
      AC20 = MFMA_(a3, BH203, AC20); AC21 = MFMA_(a3, BH213, AC21);
      AC30 = MFMA_(a3, BH303, AC30); AC31 = MFMA_(a3, BH313, AC31);
    }

    // ---- Reduction: wave partials -> Gs[wave] ----
#pragma unroll
    for (int rr = 0; rr < 4; ++rr) {
      int row = q * 4 + rr;
      Gs[wave][row][n16]       = AC00[rr];
      Gs[wave][row][16 + n16]  = AC01[rr];
      Gs[wave][row][32 + n16]  = AC10[rr];
      Gs[wave][row][48 + n16]  = AC11[rr];
      Gs[wave][row][64 + n16]  = AC20[rr];
      Gs[wave][row][80 + n16]  = AC21[rr];
      Gs[wave][row][96 + n16]  = AC30[rr];
      Gs[wave][row][112 + n16] = AC31[rr];
    }
    __syncthreads();  // S2: the one barrier per step

    // ---- LSTM cell: sum 8 wave-partials; fast nonlinearities ----
    {
      float xi = 0.f, xf = 0.f, xg = 0.f, xo = 0.f;
#pragma unroll
      for (int w2 = 0; w2 < 8; ++w2) {
        xi += Gs[w2][r_e][c_e];
        xf += Gs[w2][r_e][32 + c_e];
        xg += Gs[w2][r_e][64 + c_e];
        xo += Gs[w2][r_e][96 + c_e];
      }
      float iv = fsigmoid_(xi);
      float fv = fsigmoid_(xf);
      float gv = fsoftplus_(xg);
      float ov = fsigmoid_(xo);
      c_state = fv * c_state + iv * gv;
      float hv = ov * fsoftplus_(c_state);
      if (t == NT - 1) {
        hlast[grow * NH + hcol] = hv;
      } else {
        // 8B packed publish into FRAGMENT layout (consecutive c8 in octet)
        float hn1 = __shfl_xor(hv, 1);
        __hip_bfloat162 pk;
        pk.x = (__hip_bfloat16)hv; pk.y = (__hip_bfloat16)hn1;
        unsigned int p = *(unsigned int*)&pk;
        unsigned int po = (unsigned int)__shfl_xor((int)p, 2);
        if ((c_e & 3) == 0) {
          unsigned long long v = ((unsigned long long)po << 32) | p;
          __hip_atomic_store(
              (unsigned long long*)(hfrag + ((t + 1) & 1) * 131072 + pub_off),
              v, __ATOMIC_RELAXED, __HIP_MEMORY_SCOPE_AGENT);
        }
      }
    }

    if (t < NT - 1) {
      // ---- Per-wave release: own stores drained (vmcnt), then sub-slot ----
      if (lane == 0) {
        __hip_atomic_store(&slots[my_slot], (unsigned)(t + 1),
                           __ATOMIC_RELEASE, __HIP_MEMORY_SCOPE_AGENT);
      }
      // ---- Hidden in the poll wait: x(t+1) frag + x-GEMM + acc init ----
      XF = *(const bf16x8*)(xb + ((t + 1) * NB + m_blk * 16 + n16) * ND
                            + wave * 32 + q * 8);
      XPHASE()
    }
  }
#undef XPHASE
#undef AL
#undef MFMA_
}

// ---------------------------------------------------------------------------
// Kernel 3: projection head. 32 blocks x 128 thr; 4 batch rows per block.
// ---------------------------------------------------------------------------
__global__ __launch_bounds__(128) void proj_kernel(
    const float* __restrict__ hlast,
    const float* __restrict__ Wm, const float* __restrict__ bm,
    const float* __restrict__ Wv, const float* __restrict__ bv,
    const float* __restrict__ eps, float* __restrict__ out) {
  __shared__ float hs[4][NH];
  const int bb = blockIdx.x * 4;
  for (int idx = threadIdx.x; idx < 4 * NH; idx += 128)
    hs[idx >> 10][idx & (NH - 1)] = hlast[(bb + (idx >> 10)) * NH + (idx & (NH - 1))];
  __syncthreads();
  const int z = threadIdx.x;
  float am[4] = {0.f, 0.f, 0.f, 0.f};
  float av[4] = {0.f, 0.f, 0.f, 0.f};
#pragma unroll 8
  for (int k = 0; k < NH; ++k) {
    float wm = Wm[k * NZ + z];
    float wv = Wv[k * NZ + z];
#pragma unroll
    for (int r = 0; r < 4; ++r) {
      am[r] += hs[r][k] * wm;
      av[r] += hs[r][k] * wv;
    }
  }
#pragma unroll
  for (int r = 0; r < 4; ++r) {
    int b = bb + r;
    float mu = am[r] + bm[z];
    float lv = av[r] + bv[z];
    float zz = mu + eps[b * NZ + z] * expf(0.5f * lv);
    out[b * NZ + z] = mu;
    out[NB * NZ + b * NZ + z] = lv;
    out[2 * NB * NZ + b * NZ + z] = zz;
  }
}

// ---------------------------------------------------------------------------
extern "C" void kernel_launch(void* const* d_in, const int* in_sizes, int n_in,
                              void* d_out, int out_size, void* d_ws, size_t ws_size,
                              hipStream_t stream) {
  const float* x   = (const float*)d_in[0];
  const float* W   = (const float*)d_in[1];
  const float* U   = (const float*)d_in[2];
  const float* b   = (const float*)d_in[3];
  const float* Wm  = (const float*)d_in[4];
  const float* bm  = (const float*)d_in[5];
  const float* Wv  = (const float*)d_in[6];
  const float* bv  = (const float*)d_in[7];
  const float* eps = (const float*)d_in[8];

  // Workspace layout:
  //   [0,       524288)   hfrag: 2 x 8 x 32 x 512 bf16 (fragment layout)
  //   [524288,  1048576)  hlast: B x H fp32
  //   [1048576, 1056768)  slots: 2048 x u32 (8 KB)
  //   [1056768, +33.5MB)  xb: T x B x D bf16
  char* ws = (char*)d_ws;
  __bf16* hfrag = (__bf16*)ws;
  float* hlast = (float*)(ws + 524288);
  unsigned int* slots = (unsigned int*)(ws + 1048576);
  __bf16* xb = (__bf16*)(ws + 1048576 + 8192);

  hipMemsetAsync(hfrag, 0, 262144, stream);              // h(0) = 0 (buf 0)
  hipMemsetAsync(slots, 0, 2048 * sizeof(unsigned int), stream);

  convert_x_kernel<<<dim3((NB * NT * ND) / 4 / 256), dim3(256), 0, stream>>>(
      (const float4*)x, xb);

  void* args[] = {(void*)&xb, (void*)&W, (void*)&U, (void*)&b,
                  (void*)&hfrag, (void*)&hlast, (void*)&slots};
  hipLaunchCooperativeKernel(reinterpret_cast<void*>(lstm_persistent),
                             dim3(256), dim3(512), args, 0, stream);

  proj_kernel<<<dim3(32), dim3(128), 0, stream>>>(hlast, Wm, bm, Wv, bv, eps,
                                                  (float*)d_out);
}